// Round 2
// baseline (107.957 us; speedup 1.0000x reference)
//
#include <hip/hip_runtime.h>

#define V_DIM 128000
#define K_TOP 50
#define NBINS 2048
#define CPB 8                       // chunks per row
#define CHUNK (V_DIM / CPB)         // 16000
#define CHUNK4 (CHUNK / 4)          // 4000
#define CAPB 256                    // per-chunk candidate capacity
#define CLCAP 2048                  // per-row candidate capacity (CPB*CAPB)

struct __align__(16) RowParams { unsigned thr; int idxcut; float lnS; float pad; };

__device__ __forceinline__ unsigned key_of(float x) {
    unsigned b = __float_as_uint(x);
    return b ^ (unsigned)((((int)b) >> 31) | 0x80000000);
}
__device__ __forceinline__ float val_of(unsigned u) {
    unsigned b = u ^ (unsigned)(((~(int)u) >> 31) | 0x80000000);
    return __uint_as_float(b);
}

// descending scan over a 2048-bin histogram (hist + 1024 pair-sums + 64 super-sums);
// returns first bin (from top) where cumulative count reaches K, and cum above it.
__device__ void scan_desc(const unsigned* __restrict__ hist,
                          const unsigned* __restrict__ chunkA,
                          const unsigned* __restrict__ superA,
                          int K, unsigned* out_b1, unsigned* out_cum) {
    unsigned cum = 0; int b1 = 0; bool done = false;
    for (int s = 63; s >= 0 && !done; --s) {
        if (cum + superA[s] >= (unsigned)K) {
            for (int c = 16 * s + 15; c >= 16 * s && !done; --c) {
                if (cum + chunkA[c] >= (unsigned)K) {
                    for (int b = 2 * c + 1; b >= 2 * c && !done; --b) {
                        if (cum + hist[b] >= (unsigned)K) { b1 = b; done = true; }
                        else cum += hist[b];
                    }
                } else cum += chunkA[c];
            }
        } else cum += superA[s];
    }
    *out_b1 = (unsigned)b1; *out_cum = cum;
}

// ---------------- Kernel 1: per-chunk hist + local-topK candidates + exp partial ----
__global__ __launch_bounds__(512, 4)
void k1_hist_collect(const float* __restrict__ x, uint2* __restrict__ cand,
                     unsigned* __restrict__ cnts, double* __restrict__ psum) {
    __shared__ unsigned hist[2][NBINS];
    __shared__ unsigned chunkA[NBINS / 2];
    __shared__ unsigned superA[64];
    __shared__ double   wsum[8];
    __shared__ unsigned s_b1loc;
    __shared__ unsigned s_cnt;
    const int t = threadIdx.x;
    const int bid = blockIdx.x;
    const int row = bid >> 3, ch = bid & 7;
    const float4* __restrict__ x4 = (const float4*)(x + (size_t)row * V_DIM + ch * CHUNK);

    for (int i = t; i < 2 * NBINS; i += 512) ((unsigned*)hist)[i] = 0;
    if (t == 0) s_cnt = 0;
    __syncthreads();
    const int h = (t >> 6) & 1;   // split hist by wave parity: halves hot-bin serialization
    for (int j = t; j < CHUNK4; j += 512) {
        float4 v = x4[j];
        atomicAdd(&hist[h][key_of(v.x) >> 21], 1u);
        atomicAdd(&hist[h][key_of(v.y) >> 21], 1u);
        atomicAdd(&hist[h][key_of(v.z) >> 21], 1u);
        atomicAdd(&hist[h][key_of(v.w) >> 21], 1u);
    }
    __syncthreads();
    for (int i = t; i < NBINS; i += 512) hist[0][i] += hist[1][i];
    __syncthreads();
    for (int i = t; i < NBINS / 2; i += 512) chunkA[i] = hist[0][2 * i] + hist[0][2 * i + 1];
    __syncthreads();
    if (t < 64) {
        unsigned s = 0;
        #pragma unroll
        for (int c = 0; c < 16; ++c) s += chunkA[t * 16 + c];
        superA[t] = s;
    }
    __syncthreads();
    if (t == 0) {
        unsigned b1, cum;
        scan_desc(hist[0], chunkA, superA, K_TOP, &b1, &cum);
        s_b1loc = b1;
    }
    __syncthreads();
    const unsigned kmin = s_b1loc << 21;   // local cutoff <= global cutoff bin base
    uint2* __restrict__ my = cand + (size_t)bid * CAPB;
    const int ibase = ch * CHUNK;
    float lsum = 0.f;
    for (int j = t; j < CHUNK4; j += 512) {   // L2-hot re-read
        float4 v = x4[j];
        lsum += __expf(v.x) + __expf(v.y) + __expf(v.z) + __expf(v.w);
        unsigned u0 = key_of(v.x), u1 = key_of(v.y), u2 = key_of(v.z), u3 = key_of(v.w);
        if (u0 >= kmin) { unsigned p = atomicAdd(&s_cnt, 1u); if (p < CAPB) my[p] = make_uint2(u0, (unsigned)(ibase + 4 * j)); }
        if (u1 >= kmin) { unsigned p = atomicAdd(&s_cnt, 1u); if (p < CAPB) my[p] = make_uint2(u1, (unsigned)(ibase + 4 * j + 1)); }
        if (u2 >= kmin) { unsigned p = atomicAdd(&s_cnt, 1u); if (p < CAPB) my[p] = make_uint2(u2, (unsigned)(ibase + 4 * j + 2)); }
        if (u3 >= kmin) { unsigned p = atomicAdd(&s_cnt, 1u); if (p < CAPB) my[p] = make_uint2(u3, (unsigned)(ibase + 4 * j + 3)); }
    }
    #pragma unroll
    for (int off = 32; off; off >>= 1) lsum += __shfl_down(lsum, off);
    if ((t & 63) == 0) wsum[t >> 6] = (double)lsum;
    __syncthreads();
    if (t == 0) {
        double d = 0.0;
        for (int w = 0; w < 8; ++w) d += wsum[w];   // fixed order: deterministic
        psum[bid] = d;
        cnts[bid] = s_cnt;                           // uncapped; k2 detects overflow
    }
}

// ---------------- Kernel 2: exact per-row selection from candidates ----------------
__global__ __launch_bounds__(256, 1)
void k2_select(const float* __restrict__ x, const uint2* __restrict__ cand,
               const unsigned* __restrict__ cnts, const double* __restrict__ psum,
               RowParams* __restrict__ params) {
    __shared__ uint2    cl[CLCAP];
    __shared__ uint2    cb[CLCAP];
    __shared__ unsigned hist[NBINS];
    __shared__ unsigned chunkA[NBINS / 2];
    __shared__ unsigned superA[64];
    __shared__ unsigned offs[CPB + 1];
    __shared__ int      s_flag;
    __shared__ unsigned s_ctot;
    __shared__ unsigned s_b1;
    __shared__ int      s_r;
    __shared__ unsigned s_cbn;
    __shared__ unsigned s_thr;
    __shared__ int      s_e;
    __shared__ int      s_idxcut;
    __shared__ double   warr[4];
    const int t = threadIdx.x;
    const int row = blockIdx.x;

    if (t == 0) {
        unsigned o = 0; int flag = 0;
        for (int b = 0; b < CPB; ++b) {
            offs[b] = o;
            unsigned c = cnts[row * CPB + b];
            if (c > CAPB) flag = 1;
            o += (c < CAPB ? c : CAPB);
        }
        offs[CPB] = o;
        s_flag = flag; s_ctot = o; s_cbn = 0;
    }
    __syncthreads();
    unsigned ctot;
    if (!s_flag) {
        for (int b = 0; b < CPB; ++b) {
            const unsigned base = offs[b], c = offs[b + 1] - offs[b];
            const uint2* __restrict__ src = cand + (size_t)(row * CPB + b) * CAPB;
            for (int j = t; j < (int)c; j += 256) cl[base + j] = src[j];
        }
        ctot = s_ctot;
    } else {
        // fallback (practically never taken): full-row hist + collect
        for (int i = t; i < NBINS; i += 256) hist[i] = 0;
        __syncthreads();
        const float4* __restrict__ x4 = (const float4*)(x + (size_t)row * V_DIM);
        for (int j = t; j < V_DIM / 4; j += 256) {
            float4 v = x4[j];
            atomicAdd(&hist[key_of(v.x) >> 21], 1u);
            atomicAdd(&hist[key_of(v.y) >> 21], 1u);
            atomicAdd(&hist[key_of(v.z) >> 21], 1u);
            atomicAdd(&hist[key_of(v.w) >> 21], 1u);
        }
        __syncthreads();
        for (int i = t; i < NBINS / 2; i += 256) chunkA[i] = hist[2 * i] + hist[2 * i + 1];
        __syncthreads();
        if (t < 64) {
            unsigned s = 0;
            #pragma unroll
            for (int c = 0; c < 16; ++c) s += chunkA[t * 16 + c];
            superA[t] = s;
        }
        __syncthreads();
        if (t == 0) {
            unsigned b1, cum;
            scan_desc(hist, chunkA, superA, K_TOP, &b1, &cum);
            s_b1 = b1; s_ctot = 0;
        }
        __syncthreads();
        const unsigned kmin = s_b1 << 21;
        for (int j = t; j < V_DIM / 4; j += 256) {
            float4 v = x4[j];
            unsigned u0 = key_of(v.x), u1 = key_of(v.y), u2 = key_of(v.z), u3 = key_of(v.w);
            if (u0 >= kmin) { unsigned p = atomicAdd(&s_ctot, 1u); if (p < CLCAP) cl[p] = make_uint2(u0, (unsigned)(4 * j)); }
            if (u1 >= kmin) { unsigned p = atomicAdd(&s_ctot, 1u); if (p < CLCAP) cl[p] = make_uint2(u1, (unsigned)(4 * j + 1)); }
            if (u2 >= kmin) { unsigned p = atomicAdd(&s_ctot, 1u); if (p < CLCAP) cl[p] = make_uint2(u2, (unsigned)(4 * j + 2)); }
            if (u3 >= kmin) { unsigned p = atomicAdd(&s_ctot, 1u); if (p < CLCAP) cl[p] = make_uint2(u3, (unsigned)(4 * j + 3)); }
        }
        __syncthreads();
        ctot = (s_ctot < CLCAP) ? s_ctot : CLCAP;
    }
    // common: hist over candidates -> exact cutoff bin + rank
    for (int i = t; i < NBINS; i += 256) hist[i] = 0;
    __syncthreads();
    for (int j = t; j < (int)ctot; j += 256) atomicAdd(&hist[cl[j].x >> 21], 1u);
    __syncthreads();
    for (int i = t; i < NBINS / 2; i += 256) chunkA[i] = hist[2 * i] + hist[2 * i + 1];
    __syncthreads();
    if (t < 64) {
        unsigned s = 0;
        #pragma unroll
        for (int c = 0; c < 16; ++c) s += chunkA[t * 16 + c];
        superA[t] = s;
    }
    __syncthreads();
    if (t == 0) {
        unsigned b1, cum;
        scan_desc(hist, chunkA, superA, K_TOP, &b1, &cum);
        s_b1 = b1; s_r = K_TOP - (int)cum;
    }
    __syncthreads();
    const unsigned b1 = s_b1;
    const int r = s_r;
    for (int j = t; j < (int)ctot; j += 256)
        if ((cl[j].x >> 21) == b1) { unsigned p = atomicAdd(&s_cbn, 1u); cb[p] = cl[j]; }
    __syncthreads();
    const int cn = (int)s_cbn;
    // r-th largest key among cutoff-bin candidates (with multiplicity)
    for (int j = t; j < cn; j += 256) {
        unsigned uj = cb[j].x; int g = 0, eq = 0;
        for (int k = 0; k < cn; ++k) {
            unsigned uk = cb[k].x;
            g += (uk > uj) ? 1 : 0;
            eq += (uk == uj) ? 1 : 0;
        }
        if (g < r && r <= g + eq) { s_thr = uj; s_e = r - g; }
    }
    __syncthreads();
    const unsigned thr = s_thr; const int e = s_e;
    // e-th smallest index among ties (top_k masks lowest indices first)
    for (int j = t; j < cn; j += 256) {
        if (cb[j].x == thr) {
            int ij = (int)cb[j].y, rank = 0;
            for (int k = 0; k < cn; ++k)
                rank += (cb[k].x == thr && (int)cb[k].y < ij) ? 1 : 0;
            if (rank == e - 1) s_idxcut = ij;
        }
    }
    __syncthreads();
    const int idxcut = s_idxcut;
    // S = sum(exp(x)) - sum over masked (deterministic tree reduce, double)
    double ms = 0.0;
    for (int j = t; j < (int)ctot; j += 256) {
        unsigned u = cl[j].x;
        if (u > thr || (u == thr && (int)cl[j].y <= idxcut))
            ms += exp((double)val_of(u));
    }
    #pragma unroll
    for (int off = 32; off; off >>= 1) ms += __shfl_down(ms, off);
    if ((t & 63) == 0) warr[t >> 6] = ms;
    __syncthreads();
    if (t == 0) {
        double sall = 0.0;
        for (int b = 0; b < CPB; ++b) sall += psum[row * CPB + b];
        double S = sall - (warr[0] + warr[1] + warr[2] + warr[3]);
        RowParams p; p.thr = thr; p.idxcut = idxcut; p.lnS = (float)log(S); p.pad = 0.f;
        params[row] = p;
    }
}

// ---------------- Kernel 3: masked softmax write ----------------
__global__ __launch_bounds__(256, 8)
void k3_write(const float* __restrict__ x, const RowParams* __restrict__ params,
              float* __restrict__ out) {
    const int row = blockIdx.y;
    const int seg = blockIdx.x;                 // 32 segs x 1000 float4
    const int t = threadIdx.x;
    const RowParams p = params[row];
    const unsigned thr = p.thr; const int idxcut = p.idxcut; const float lnS = p.lnS;
    const float4* __restrict__ x4 = (const float4*)(x + (size_t)row * V_DIM) + seg * 1000;
    float4* __restrict__ o4 = (float4*)(out + (size_t)row * V_DIM) + seg * 1000;
    const int ibase = seg * 4000;
    for (int j = t; j < 1000; j += 256) {
        float4 v = x4[j];
        float4 o;
        {
            unsigned u = key_of(v.x); int i = ibase + 4 * j;
            o.x = (u > thr || (u == thr && i <= idxcut)) ? 0.f : __expf(v.x - lnS);
        }
        {
            unsigned u = key_of(v.y); int i = ibase + 4 * j + 1;
            o.y = (u > thr || (u == thr && i <= idxcut)) ? 0.f : __expf(v.y - lnS);
        }
        {
            unsigned u = key_of(v.z); int i = ibase + 4 * j + 2;
            o.z = (u > thr || (u == thr && i <= idxcut)) ? 0.f : __expf(v.z - lnS);
        }
        {
            unsigned u = key_of(v.w); int i = ibase + 4 * j + 3;
            o.w = (u > thr || (u == thr && i <= idxcut)) ? 0.f : __expf(v.w - lnS);
        }
        o4[j] = o;
    }
}

extern "C" void kernel_launch(void* const* d_in, const int* in_sizes, int n_in,
                              void* d_out, int out_size, void* d_ws, size_t ws_size,
                              hipStream_t stream) {
    const float* scores = (const float*)d_in[0];
    float* out = (float*)d_out;
    const int B = in_sizes[0] / V_DIM;
    const int NBLK1 = B * CPB;

    char* wsb = (char*)d_ws;
    uint2*     cand   = (uint2*)wsb;                       // NBLK1*CAPB*8 B = 4 MB @ B=256
    size_t off = (size_t)NBLK1 * CAPB * sizeof(uint2);
    unsigned*  cnts   = (unsigned*)(wsb + off);            // NBLK1*4 B
    off += (size_t)NBLK1 * sizeof(unsigned);
    off = (off + 15) & ~(size_t)15;
    double*    psum   = (double*)(wsb + off);              // NBLK1*8 B
    off += (size_t)NBLK1 * sizeof(double);
    off = (off + 15) & ~(size_t)15;
    RowParams* params = (RowParams*)(wsb + off);           // B*16 B

    hipLaunchKernelGGL(k1_hist_collect, dim3(NBLK1), dim3(512), 0, stream,
                       scores, cand, cnts, psum);
    hipLaunchKernelGGL(k2_select, dim3(B), dim3(256), 0, stream,
                       scores, cand, cnts, psum, params);
    hipLaunchKernelGGL(k3_write, dim3(32, B), dim3(256), 0, stream,
                       scores, params, out);
}